// Round 3
// baseline (67.962 us; speedup 1.0000x reference)
//
#include <hip/hip_runtime.h>
#include <math.h>

#define EPS_F 1e-10f

typedef __attribute__((ext_vector_type(2))) float f2;
typedef __attribute__((ext_vector_type(2))) unsigned int u2;

__device__ __forceinline__ f2 v_fabs(f2 x) {
  u2 u = __builtin_bit_cast(u2, x);
  u &= 0x7fffffffu;
  return __builtin_bit_cast(f2, u);
}
__device__ __forceinline__ f2 v_max(f2 a, f2 b) { return __builtin_elementwise_max(a, b); }
__device__ __forceinline__ f2 v_min(f2 a, f2 b) { return __builtin_elementwise_min(a, b); }
__device__ __forceinline__ f2 v_log(f2 x) {
  f2 r; r.x = __logf(x.x); r.y = __logf(x.y); return r;
}
__device__ __forceinline__ f2 v_rcp(f2 x) {
  f2 r; r.x = __builtin_amdgcn_rcpf(x.x); r.y = __builtin_amdgcn_rcpf(x.y); return r;
}
__device__ __forceinline__ f2 v_sqrt(f2 x) {
  f2 r; r.x = __builtin_amdgcn_sqrtf(x.x); r.y = __builtin_amdgcn_sqrtf(x.y); return r;
}
__device__ __forceinline__ f2 v_cos(f2 x) {
  f2 r; r.x = __cosf(x.x); r.y = __cosf(x.y); return r;
}

// sanitize: non-finite -> EPS, else abs  (matches nan_to_num(nan/inf->eps) + abs)
__device__ __forceinline__ f2 v_san(f2 v) {
  f2 a = v_fabs(v);
  f2 r;
  r.x = (a.x <= __FLT_MAX__) ? a.x : EPS_F;
  r.y = (a.y <= __FLT_MAX__) ? a.y : EPS_F;
  return r;
}

// acos via minimax poly (|err| ~ 2e-8 rad), vectorized over the pair
__device__ __forceinline__ f2 v_acos(f2 r) {
  const f2 t = v_fabs(r);
  const f2 s = v_sqrt(1.0f - t);
  f2 p = f2{-0.0012624911f, -0.0012624911f};
  p = p * t +  0.0066700901f;
  p = p * t + -0.0170881256f;
  p = p * t +  0.0308918810f;
  p = p * t + -0.0501743046f;
  p = p * t +  0.0889789874f;
  p = p * t + -0.2145988016f;
  p = p * t +  1.5707963050f;
  const f2 ac = s * p;                         // acos(|r|)
  f2 res;
  res.x = (r.x < 0.0f) ? (3.14159265358979f - ac.x) : ac.x;
  res.y = (r.y < 0.0f) ? (3.14159265358979f - ac.y) : ac.y;
  return res;
}

// logm of two symmetric 3x3 matrices in lockstep (component 0 = D1, 1 = D2).
// Inputs pre-sanitized. Output unique entries [m00,m01,m02,m11,m12,m22].
__device__ __forceinline__ void logm3v(f2 a00, f2 a01, f2 a02,
                                       f2 a11, f2 a12, f2 a22,
                                       f2 L[6]) {
  const f2 q   = (a00 + a11 + a22) * (1.0f / 3.0f);
  const f2 b00 = a00 - q, b11 = a11 - q, b22 = a22 - q;
  const f2 p2  = b00 * b00 + b11 * b11 + b22 * b22 +
                 2.0f * (a01 * a01 + a02 * a02 + a12 * a12);

  // guard: keep p away from 0 so all downstream denominators (>= ~p^2) stay
  // in normal range. Isolated-extreme gap >= 1.5p bounds inv_den_a by ~rcp(4.5p^2).
  f2 p = v_sqrt(p2 * (1.0f / 6.0f));
  p = v_max(p, 1e-5f * q + 1e-35f);

  const f2 pinv = v_rcp(p);
  const f2 detB = b00 * (b11 * b22 - a12 * a12)
                - a01 * (a01 * b22 - a12 * a02)
                + a02 * (a01 * a12 - b11 * a02);
  f2 r = detB * 0.5f * pinv * pinv * pinv;
  r = v_min(f2{1.0f, 1.0f}, v_max(f2{-1.0f, -1.0f}, r));
  const f2 phi  = v_acos(r) * (1.0f / 3.0f);
  const f2 twop = 2.0f * p;
  const f2 l1 = q + twop * v_cos(phi);                          // largest
  const f2 l3 = q + twop * v_cos(phi + 2.0943951023931953f);    // smallest
  const f2 l2 = 3.0f * q - l1 - l3;

  // A^2 (symmetric)
  const f2 s00 = a00 * a00 + a01 * a01 + a02 * a02;
  const f2 s01 = a00 * a01 + a01 * a11 + a02 * a12;
  const f2 s02 = a00 * a02 + a01 * a12 + a02 * a22;
  const f2 s11 = a01 * a01 + a11 * a11 + a12 * a12;
  const f2 s12 = a01 * a02 + a11 * a12 + a12 * a22;
  const f2 s22 = a02 * a02 + a12 * a12 + a22 * a22;

  // isolated extreme eigenvalue = alpha; beta = middle; gamma = other extreme
  const f2 g12 = l1 - l2, g23 = l2 - l3;
  f2 alpha, gamma;
  alpha.x = (g12.x >= g23.x) ? l1.x : l3.x;
  gamma.x = (g12.x >= g23.x) ? l3.x : l1.x;
  alpha.y = (g12.y >= g23.y) ? l1.y : l3.y;
  gamma.y = (g12.y >= g23.y) ? l3.y : l1.y;
  const f2 beta = l2;

  const f2 f_a = v_log(alpha + EPS_F) + EPS_F;
  const f2 f_b = v_log(beta  + EPS_F) + EPS_F;
  const f2 f_g = v_log(gamma + EPS_F) + EPS_F;

  // P_alpha = (A - beta I)(A - gamma I) / ((alpha-beta)(alpha-gamma))
  const f2 inv_den_a = v_rcp((alpha - beta) * (alpha - gamma));
  const f2 sbg = beta + gamma, pbg = beta * gamma;
  const f2 pa00 = (s00 - sbg * a00 + pbg) * inv_den_a;
  const f2 pa01 = (s01 - sbg * a01)       * inv_den_a;
  const f2 pa02 = (s02 - sbg * a02)       * inv_den_a;
  const f2 pa11 = (s11 - sbg * a11 + pbg) * inv_den_a;
  const f2 pa12 = (s12 - sbg * a12)       * inv_den_a;
  const f2 pa22 = (s22 - sbg * a22 + pbg) * inv_den_a;

  // N = (A - alpha I)(A - beta I)
  const f2 sab = alpha + beta, pab = alpha * beta;
  const f2 n00 = s00 - sab * a00 + pab;
  const f2 n01 = s01 - sab * a01;
  const f2 n02 = s02 - sab * a02;
  const f2 n11 = s11 - sab * a11 + pab;
  const f2 n12 = s12 - sab * a12;
  const f2 n22 = s22 - sab * a22 + pab;

  // divided difference of f over the close pair (beta,gamma), single rcp:
  //   wide:   cg = (f_g - f_b) / (gap * (gamma - alpha))
  //   narrow: cg = 1 / ((mid + EPS) * (gamma - alpha))
  const f2 gap = gamma - beta;
  const f2 ga  = gamma - alpha;
  const f2 agap = v_fabs(gap);
  const f2 thr  = 1e-5f * v_max(v_fabs(beta), v_fabs(gamma));
  const f2 mid  = 0.5f * (beta + gamma) + EPS_F;
  f2 num, den;
  num.x = (agap.x > thr.x) ? (f_g.x - f_b.x) : 1.0f;
  den.x = (agap.x > thr.x) ? (gap.x * ga.x) : (mid.x * ga.x);
  num.y = (agap.y > thr.y) ? (f_g.y - f_b.y) : 1.0f;
  den.y = (agap.y > thr.y) ? (gap.y * ga.y) : (mid.y * ga.y);
  const f2 cg = num * v_rcp(den);

  // logm = f_b*I + (f_a - f_b)*P_alpha + cg*N
  const f2 w = f_a - f_b;
  L[0] = f_b + w * pa00 + cg * n00;
  L[1] =       w * pa01 + cg * n01;
  L[2] =       w * pa02 + cg * n02;
  L[3] = f_b + w * pa11 + cg * n11;
  L[4] =       w * pa12 + cg * n12;
  L[5] = f_b + w * pa22 + cg * n22;
}

__device__ __forceinline__ float pair_loss(float a0, float a1, float a2,
                                           float a4, float a5, float a8,
                                           float b0, float b1, float b2,
                                           float b4, float b5, float b8) {
  f2 L[6];
  logm3v(v_san(f2{a0, b0}), v_san(f2{a1, b1}), v_san(f2{a2, b2}),
         v_san(f2{a4, b4}), v_san(f2{a5, b5}), v_san(f2{a8, b8}), L);
  const float d0 = L[0].x - L[0].y;
  const float d1 = L[1].x - L[1].y;
  const float d2 = L[2].x - L[2].y;
  const float d3 = L[3].x - L[3].y;
  const float d4 = L[4].x - L[4].y;
  const float d5 = L[5].x - L[5].y;
  // full 3x3 Frobenius: off-diagonals count twice
  return d0 * d0 + d3 * d3 + d5 * d5 + 2.0f * (d1 * d1 + d2 * d2 + d4 * d4);
}

__global__ void __launch_bounds__(256)
leloss_partial(const float* __restrict__ d1, const float* __restrict__ d2,
               float* __restrict__ partial, int nfull, int nmat) {
  const int t = blockIdx.x * blockDim.x + threadIdx.x;
  float acc = 0.0f;

  if (t < nfull) {
    // 4 matrix pairs per thread: 36 floats = 9 aligned float4 per tensor
    float a[36], b[36];
    const float4* p1 = reinterpret_cast<const float4*>(d1) + (size_t)t * 9;
    const float4* p2 = reinterpret_cast<const float4*>(d2) + (size_t)t * 9;
#pragma unroll
    for (int i = 0; i < 9; ++i) {
      const float4 v = p1[i];
      a[4 * i + 0] = v.x; a[4 * i + 1] = v.y;
      a[4 * i + 2] = v.z; a[4 * i + 3] = v.w;
    }
#pragma unroll
    for (int i = 0; i < 9; ++i) {
      const float4 v = p2[i];
      b[4 * i + 0] = v.x; b[4 * i + 1] = v.y;
      b[4 * i + 2] = v.z; b[4 * i + 3] = v.w;
    }
#pragma unroll
    for (int m = 0; m < 4; ++m) {
      acc += pair_loss(a[9 * m + 0], a[9 * m + 1], a[9 * m + 2],
                       a[9 * m + 4], a[9 * m + 5], a[9 * m + 8],
                       b[9 * m + 0], b[9 * m + 1], b[9 * m + 2],
                       b[9 * m + 4], b[9 * m + 5], b[9 * m + 8]);
    }
  } else if (t == nfull) {
    // scalar tail (nmat % 4 matrices) — empty for this problem size
    for (int j = 4 * nfull; j < nmat; ++j) {
      const size_t base = (size_t)j * 9;
      acc += pair_loss(d1[base + 0], d1[base + 1], d1[base + 2],
                       d1[base + 4], d1[base + 5], d1[base + 8],
                       d2[base + 0], d2[base + 1], d2[base + 2],
                       d2[base + 4], d2[base + 5], d2[base + 8]);
    }
  }

  // wave reduce (64 lanes)
#pragma unroll
  for (int off = 32; off > 0; off >>= 1) acc += __shfl_down(acc, off, 64);

  __shared__ float wsum[4];
  const int lane = threadIdx.x & 63;
  const int wid  = threadIdx.x >> 6;
  if (lane == 0) wsum[wid] = acc;
  __syncthreads();
  if (threadIdx.x == 0) {
    partial[blockIdx.x] = wsum[0] + wsum[1] + wsum[2] + wsum[3];
  }
}

__global__ void __launch_bounds__(256)
leloss_reduce(const float* __restrict__ partial, int n,
              float* __restrict__ out, double inv_count) {
  double s = 0.0;
  for (int i = threadIdx.x; i < n; i += 256) s += (double)partial[i];
#pragma unroll
  for (int off = 32; off > 0; off >>= 1) s += __shfl_down(s, off, 64);

  __shared__ double wsum[4];
  const int lane = threadIdx.x & 63;
  const int wid  = threadIdx.x >> 6;
  if (lane == 0) wsum[wid] = s;
  __syncthreads();
  if (threadIdx.x == 0) {
    const double total = wsum[0] + wsum[1] + wsum[2] + wsum[3];
    out[0] = (float)(total * inv_count);
  }
}

extern "C" void kernel_launch(void* const* d_in, const int* in_sizes, int n_in,
                              void* d_out, int out_size, void* d_ws, size_t ws_size,
                              hipStream_t stream) {
  const float* d1 = (const float*)d_in[0];
  const float* d2 = (const float*)d_in[1];
  float* out = (float*)d_out;
  float* partial = (float*)d_ws;

  const long long nelem = (long long)in_sizes[0];
  const int nmat  = (int)(nelem / 9);
  const int nfull = nmat / 4;

  const int nthreads = nfull + 1;             // +1 thread owns the scalar tail
  const int nblocks  = (nthreads + 255) / 256;

  leloss_partial<<<nblocks, 256, 0, stream>>>(d1, d2, partial, nfull, nmat);

  const double inv_count = 1.0 / ((double)nmat * 9.0);
  leloss_reduce<<<1, 256, 0, stream>>>(partial, nblocks, out, inv_count);
}

// Round 4
// 33.654 us; speedup vs baseline: 2.0195x; 2.0195x over previous
//
#include <hip/hip_runtime.h>
#include <math.h>

#define EPS_F 1e-10f

typedef __attribute__((ext_vector_type(2))) float f2;
typedef __attribute__((ext_vector_type(2))) unsigned int u2;

__device__ __forceinline__ f2 v_fabs(f2 x) {
  u2 u = __builtin_bit_cast(u2, x);
  u &= 0x7fffffffu;
  return __builtin_bit_cast(f2, u);
}
__device__ __forceinline__ f2 v_max(f2 a, f2 b) { return __builtin_elementwise_max(a, b); }
__device__ __forceinline__ f2 v_min(f2 a, f2 b) { return __builtin_elementwise_min(a, b); }
__device__ __forceinline__ f2 v_log(f2 x) {
  f2 r; r.x = __logf(x.x); r.y = __logf(x.y); return r;
}
__device__ __forceinline__ f2 v_rcp(f2 x) {
  f2 r; r.x = __builtin_amdgcn_rcpf(x.x); r.y = __builtin_amdgcn_rcpf(x.y); return r;
}
__device__ __forceinline__ f2 v_sqrt(f2 x) {
  f2 r; r.x = __builtin_amdgcn_sqrtf(x.x); r.y = __builtin_amdgcn_sqrtf(x.y); return r;
}
__device__ __forceinline__ f2 v_cos(f2 x) {
  f2 r; r.x = __cosf(x.x); r.y = __cosf(x.y); return r;
}

// sanitize: non-finite -> EPS, else abs (matches nan_to_num(nan/inf->eps) + abs)
__device__ __forceinline__ f2 v_san(f2 v) {
  f2 a = v_fabs(v);
  f2 r;
  r.x = (a.x <= __FLT_MAX__) ? a.x : EPS_F;
  r.y = (a.y <= __FLT_MAX__) ? a.y : EPS_F;
  return r;
}

// acos via minimax poly (|err| ~ 2e-8 rad), vectorized over the pair
__device__ __forceinline__ f2 v_acos(f2 r) {
  const f2 t = v_fabs(r);
  const f2 s = v_sqrt(1.0f - t);
  f2 p = f2{-0.0012624911f, -0.0012624911f};
  p = p * t +  0.0066700901f;
  p = p * t + -0.0170881256f;
  p = p * t +  0.0308918810f;
  p = p * t + -0.0501743046f;
  p = p * t +  0.0889789874f;
  p = p * t + -0.2145988016f;
  p = p * t +  1.5707963050f;
  const f2 ac = s * p;                         // acos(|r|)
  f2 res;
  res.x = (r.x < 0.0f) ? (3.14159265358979f - ac.x) : ac.x;
  res.y = (r.y < 0.0f) ? (3.14159265358979f - ac.y) : ac.y;
  return res;
}

// Fused: logm(D1) - logm(D2) Frobenius^2 for one matrix pair, D1/D2 packed in
// f2 lanes (.x = D1, .y = D2). Inputs pre-sanitized. No arrays — named regs only.
__device__ __forceinline__ float pair_loss(f2 a00, f2 a01, f2 a02,
                                           f2 a11, f2 a12, f2 a22) {
  const f2 q   = (a00 + a11 + a22) * (1.0f / 3.0f);
  const f2 b00 = a00 - q, b11 = a11 - q, b22 = a22 - q;
  const f2 p2  = b00 * b00 + b11 * b11 + b22 * b22 +
                 2.0f * (a01 * a01 + a02 * a02 + a12 * a12);

  // keep p away from 0 so all downstream denominators (~p^2) stay normal;
  // isolated-extreme gap >= 1.5p bounds inv_den_a by ~rcp(4.5 p^2)
  f2 p = v_sqrt(p2 * (1.0f / 6.0f));
  p = v_max(p, 1e-5f * q + 1e-35f);

  const f2 pinv = v_rcp(p);
  const f2 detB = b00 * (b11 * b22 - a12 * a12)
                - a01 * (a01 * b22 - a12 * a02)
                + a02 * (a01 * a12 - b11 * a02);
  f2 r = detB * 0.5f * pinv * pinv * pinv;
  r = v_min(f2{1.0f, 1.0f}, v_max(f2{-1.0f, -1.0f}, r));
  const f2 phi  = v_acos(r) * (1.0f / 3.0f);
  const f2 twop = 2.0f * p;
  const f2 l1 = q + twop * v_cos(phi);                          // largest
  const f2 l3 = q + twop * v_cos(phi + 2.0943951023931953f);    // smallest
  const f2 l2 = 3.0f * q - l1 - l3;

  // A^2 (symmetric)
  const f2 s00 = a00 * a00 + a01 * a01 + a02 * a02;
  const f2 s01 = a00 * a01 + a01 * a11 + a02 * a12;
  const f2 s02 = a00 * a02 + a01 * a12 + a02 * a22;
  const f2 s11 = a01 * a01 + a11 * a11 + a12 * a12;
  const f2 s12 = a01 * a02 + a11 * a12 + a12 * a22;
  const f2 s22 = a02 * a02 + a12 * a12 + a22 * a22;

  // isolated extreme eigenvalue = alpha; beta = middle; gamma = other extreme
  const f2 g12 = l1 - l2, g23 = l2 - l3;
  f2 alpha, gamma;
  alpha.x = (g12.x >= g23.x) ? l1.x : l3.x;
  gamma.x = (g12.x >= g23.x) ? l3.x : l1.x;
  alpha.y = (g12.y >= g23.y) ? l1.y : l3.y;
  gamma.y = (g12.y >= g23.y) ? l3.y : l1.y;
  const f2 beta = l2;

  const f2 f_a = v_log(alpha + EPS_F) + EPS_F;
  const f2 f_b = v_log(beta  + EPS_F) + EPS_F;
  const f2 f_g = v_log(gamma + EPS_F) + EPS_F;

  // P_alpha = (A - beta I)(A - gamma I) / ((alpha-beta)(alpha-gamma))
  const f2 inv_den_a = v_rcp((alpha - beta) * (alpha - gamma));
  const f2 sbg = beta + gamma, pbg = beta * gamma;

  // N = (A - alpha I)(A - beta I)
  const f2 sab = alpha + beta, pab = alpha * beta;

  // divided difference of f over the close pair (beta,gamma), single rcp
  const f2 gap = gamma - beta;
  const f2 ga  = gamma - alpha;
  const f2 agap = v_fabs(gap);
  const f2 thr  = 1e-5f * v_max(v_fabs(beta), v_fabs(gamma));
  const f2 mid  = 0.5f * (beta + gamma) + EPS_F;
  f2 num, den;
  num.x = (agap.x > thr.x) ? (f_g.x - f_b.x) : 1.0f;
  den.x = (agap.x > thr.x) ? (gap.x * ga.x) : (mid.x * ga.x);
  num.y = (agap.y > thr.y) ? (f_g.y - f_b.y) : 1.0f;
  den.y = (agap.y > thr.y) ? (gap.y * ga.y) : (mid.y * ga.y);
  const f2 cg = num * v_rcp(den);

  const f2 w = f_a - f_b;
  const f2 wd = w * inv_den_a;

  // L_ij = f_b*[i==j] + wd*Pnum_ij + cg*N_ij, fused per entry
  const f2 L0 = f_b + wd * (s00 - sbg * a00 + pbg) + cg * (s00 - sab * a00 + pab);
  const f2 L1 =       wd * (s01 - sbg * a01)       + cg * (s01 - sab * a01);
  const f2 L2 =       wd * (s02 - sbg * a02)       + cg * (s02 - sab * a02);
  const f2 L3 = f_b + wd * (s11 - sbg * a11 + pbg) + cg * (s11 - sab * a11 + pab);
  const f2 L4 =       wd * (s12 - sbg * a12)       + cg * (s12 - sab * a12);
  const f2 L5 = f_b + wd * (s22 - sbg * a22 + pbg) + cg * (s22 - sab * a22 + pab);

  const float d0 = L0.x - L0.y;
  const float d1 = L1.x - L1.y;
  const float d2 = L2.x - L2.y;
  const float d3 = L3.x - L3.y;
  const float d4 = L4.x - L4.y;
  const float d5 = L5.x - L5.y;
  // full 3x3 Frobenius: off-diagonals count twice
  return d0 * d0 + d3 * d3 + d5 * d5 + 2.0f * (d1 * d1 + d2 * d2 + d4 * d4);
}

#define PAIRS_PER_CHUNK 256
#define FLOATS_PER_CHUNK (PAIRS_PER_CHUNK * 9)   // 2304 floats = 576 float4

__global__ void __launch_bounds__(256)
leloss_partial(const float* __restrict__ d1, const float* __restrict__ d2,
               float* __restrict__ partial, int nmat, int nchunk) {
  __shared__ float sA[FLOATS_PER_CHUNK];
  __shared__ float sB[FLOATS_PER_CHUNK];

  const int tid = threadIdx.x;
  float acc = 0.0f;

  for (int c = blockIdx.x; c < nchunk; c += gridDim.x) {
    const int base = c * PAIRS_PER_CHUNK;          // first matrix of chunk
    const int rem  = nmat - base;                  // matrices in this chunk

    if (rem >= PAIRS_PER_CHUNK) {
      // full chunk: coalesced float4 staging (base*36 bytes is 16B-aligned)
      const float4* g1 = reinterpret_cast<const float4*>(d1 + (size_t)base * 9);
      const float4* g2 = reinterpret_cast<const float4*>(d2 + (size_t)base * 9);
      float4* s4A = reinterpret_cast<float4*>(sA);
      float4* s4B = reinterpret_cast<float4*>(sB);
#pragma unroll
      for (int k = 0; k < FLOATS_PER_CHUNK / 4 / 256 + 1; ++k) {
        const int idx = tid + k * 256;
        if (idx < FLOATS_PER_CHUNK / 4) { s4A[idx] = g1[idx]; s4B[idx] = g2[idx]; }
      }
    } else {
      // tail chunk: scalar staging with bounds
      const int nflt = rem * 9;
      for (int k = tid; k < nflt; k += 256) {
        sA[k] = d1[(size_t)base * 9 + k];
        sB[k] = d2[(size_t)base * 9 + k];
      }
    }
    __syncthreads();

    if (tid < rem) {
      const int o = tid * 9;   // stride-9 words: 9 coprime 32 -> 2 lanes/bank, free
      const f2 m00 = v_san(f2{sA[o + 0], sB[o + 0]});
      const f2 m01 = v_san(f2{sA[o + 1], sB[o + 1]});
      const f2 m02 = v_san(f2{sA[o + 2], sB[o + 2]});
      const f2 m11 = v_san(f2{sA[o + 4], sB[o + 4]});
      const f2 m12 = v_san(f2{sA[o + 5], sB[o + 5]});
      const f2 m22 = v_san(f2{sA[o + 8], sB[o + 8]});
      acc += pair_loss(m00, m01, m02, m11, m12, m22);
    }
    __syncthreads();
  }

  // wave reduce (64 lanes)
#pragma unroll
  for (int off = 32; off > 0; off >>= 1) acc += __shfl_down(acc, off, 64);

  __shared__ float wsum[4];
  const int lane = tid & 63;
  const int wid  = tid >> 6;
  if (lane == 0) wsum[wid] = acc;
  __syncthreads();
  if (tid == 0) {
    partial[blockIdx.x] = wsum[0] + wsum[1] + wsum[2] + wsum[3];
  }
}

__global__ void __launch_bounds__(256)
leloss_reduce(const float* __restrict__ partial, int n,
              float* __restrict__ out, double inv_count) {
  double s = 0.0;
  for (int i = threadIdx.x; i < n; i += 256) s += (double)partial[i];
#pragma unroll
  for (int off = 32; off > 0; off >>= 1) s += __shfl_down(s, off, 64);

  __shared__ double wsum[4];
  const int lane = threadIdx.x & 63;
  const int wid  = threadIdx.x >> 6;
  if (lane == 0) wsum[wid] = s;
  __syncthreads();
  if (threadIdx.x == 0) {
    const double total = wsum[0] + wsum[1] + wsum[2] + wsum[3];
    out[0] = (float)(total * inv_count);
  }
}

extern "C" void kernel_launch(void* const* d_in, const int* in_sizes, int n_in,
                              void* d_out, int out_size, void* d_ws, size_t ws_size,
                              hipStream_t stream) {
  const float* d1 = (const float*)d_in[0];
  const float* d2 = (const float*)d_in[1];
  float* out = (float*)d_out;
  float* partial = (float*)d_ws;

  const long long nelem = (long long)in_sizes[0];
  const int nmat   = (int)(nelem / 9);
  const int nchunk = (nmat + PAIRS_PER_CHUNK - 1) / PAIRS_PER_CHUNK;
  const int nblocks = nchunk < 2048 ? nchunk : 2048;

  leloss_partial<<<nblocks, 256, 0, stream>>>(d1, d2, partial, nmat, nchunk);

  const double inv_count = 1.0 / ((double)nmat * 9.0);
  leloss_reduce<<<1, 256, 0, stream>>>(partial, nblocks, out, inv_count);
}